// Round 1
// baseline (1604.555 us; speedup 1.0000x reference)
//
#include <hip/hip_runtime.h>
#include <math.h>

#define N_NODES 50000
#define N_EDGES 800000
#define N_ETOT  850000   /* E + N self-loops */
#define F_IN    32
#define HEADS   4
#define CHAN    64
#define HID     256
#define NGRAPH  1024
#define MLP_HID 2048
#define NOUT    768
#define NEG_SLOPE 0.2f

// ---------------------------------------------------------------- CSR build
__global__ __launch_bounds__(256) void hist_kernel(const int* __restrict__ ei,
                                                   int* __restrict__ deg) {
    int e = blockIdx.x * 256 + threadIdx.x;
    if (e >= N_ETOT) return;
    int d = (e < N_EDGES) ? ei[N_EDGES + e] : (e - N_EDGES);
    atomicAdd(&deg[d], 1);
}

__global__ __launch_bounds__(1024) void scan_kernel(const int* __restrict__ deg,
                                                    int* __restrict__ off,
                                                    int* __restrict__ cur) {
    __shared__ int sums[1024];
    const int t = threadIdx.x;
    const int CHK = (N_NODES + 1023) / 1024;   // 49
    int lo = t * CHK;
    int hi = min(lo + CHK, N_NODES);
    int s = 0;
    for (int i = lo; i < hi; ++i) s += deg[i];
    sums[t] = s;
    __syncthreads();
    // Hillis-Steele inclusive scan over 1024 partial sums
    for (int d = 1; d < 1024; d <<= 1) {
        int v = (t >= d) ? sums[t - d] : 0;
        __syncthreads();
        sums[t] += v;
        __syncthreads();
    }
    int run = sums[t] - s;                     // exclusive prefix
    for (int i = lo; i < hi; ++i) {
        int d0 = deg[i];
        off[i] = run;
        cur[i] = run;
        run += d0;
    }
    if (t == 1023) off[N_NODES] = run;         // = total edge count
}

__global__ __launch_bounds__(256) void scatter_kernel(const int* __restrict__ ei,
                                                      int* __restrict__ cur,
                                                      int* __restrict__ ssrc) {
    int e = blockIdx.x * 256 + threadIdx.x;
    if (e >= N_ETOT) return;
    int s, d;
    if (e < N_EDGES) { s = ei[e]; d = ei[N_EDGES + e]; }
    else             { s = e - N_EDGES; d = s; }
    int pos = atomicAdd(&cur[d], 1);
    ssrc[pos] = s;
}

// ---------------------------------------------------------------- fp32 GEMM
// C[M,Nn] = A[M,K] @ B[K,Nn] (+bias)(+relu). BM=BN=64, BK=32, 4x4/thread.
template <bool BIAS, bool RELU>
__global__ __launch_bounds__(256) void gemm_kernel(const float* __restrict__ A,
                                                   const float* __restrict__ B,
                                                   const float* __restrict__ bias,
                                                   float* __restrict__ C,
                                                   int M, int Nn, int K) {
    __shared__ float As[64][33];
    __shared__ float Bs[32][65];
    const int t = threadIdx.x;
    const int bm = blockIdx.x * 64;
    const int bn = blockIdx.y * 64;
    const int row0 = (t >> 4) << 2;   // 0..60
    const int col0 = (t & 15) << 2;   // 0..60

    float acc[4][4] = {};
    for (int k0 = 0; k0 < K; k0 += 32) {
        #pragma unroll
        for (int i = t; i < 64 * 32; i += 256) {
            int r = i >> 5, c = i & 31;
            int gr = bm + r;
            As[r][c] = (gr < M) ? A[(size_t)gr * K + k0 + c] : 0.f;
        }
        #pragma unroll
        for (int i = t; i < 32 * 64; i += 256) {
            int r = i >> 6, c = i & 63;
            Bs[r][c] = B[(size_t)(k0 + r) * Nn + bn + c];
        }
        __syncthreads();
        #pragma unroll
        for (int k = 0; k < 32; ++k) {
            float a[4], b[4];
            #pragma unroll
            for (int i = 0; i < 4; ++i) a[i] = As[row0 + i][k];
            #pragma unroll
            for (int j = 0; j < 4; ++j) b[j] = Bs[k][col0 + j];
            #pragma unroll
            for (int i = 0; i < 4; ++i)
                #pragma unroll
                for (int j = 0; j < 4; ++j)
                    acc[i][j] += a[i] * b[j];
        }
        __syncthreads();
    }
    #pragma unroll
    for (int i = 0; i < 4; ++i) {
        int r = bm + row0 + i;
        if (r >= M) break;
        #pragma unroll
        for (int j = 0; j < 4; ++j) {
            int c = bn + col0 + j;
            float v = acc[i][j];
            if (BIAS) v += bias[c];
            if (RELU) v = fmaxf(v, 0.f);
            C[(size_t)r * Nn + c] = v;
        }
    }
}

// ------------------------------------------------------- attention logits
// wave per node; lane = channel; 4 heads reduced across 64 lanes.
__global__ __launch_bounds__(256) void logits_kernel(const float* __restrict__ h,
                                                     const float* __restrict__ a_s,
                                                     const float* __restrict__ a_d,
                                                     float* __restrict__ ls,
                                                     float* __restrict__ ld) {
    const int lane = threadIdx.x & 63;
    const int wid  = threadIdx.x >> 6;
    const int node = blockIdx.x * 4 + wid;
    if (node >= N_NODES) return;
    float ss[HEADS], dd[HEADS];
    #pragma unroll
    for (int hh = 0; hh < HEADS; ++hh) {
        float v = h[(size_t)node * HID + hh * CHAN + lane];
        ss[hh] = v * a_s[hh * CHAN + lane];
        dd[hh] = v * a_d[hh * CHAN + lane];
    }
    #pragma unroll
    for (int o = 32; o > 0; o >>= 1) {
        #pragma unroll
        for (int hh = 0; hh < HEADS; ++hh) {
            ss[hh] += __shfl_down(ss[hh], o);
            dd[hh] += __shfl_down(dd[hh], o);
        }
    }
    if (lane == 0) {
        #pragma unroll
        for (int hh = 0; hh < HEADS; ++hh) {
            ls[node * HEADS + hh] = ss[hh];
            ld[node * HEADS + hh] = dd[hh];
        }
    }
}

// --------------------------------------------------------- GAT aggregation
// wave per dst node. Pass 1: segment max (lanes parallel over edges).
// Pass 2: lanes = 64 channels x 4 heads; walk edges, accumulate w*h[src].
__device__ __forceinline__ float leaky(float x) { return fmaxf(x, NEG_SLOPE * x); }

template <bool RELU>
__global__ __launch_bounds__(256) void gat_aggregate(const float* __restrict__ h_in,
                                                     const int* __restrict__ off,
                                                     const int* __restrict__ ssrc,
                                                     const float* __restrict__ ls,
                                                     const float* __restrict__ ld,
                                                     const float* __restrict__ bias,
                                                     float* __restrict__ h_out) {
    const int lane = threadIdx.x & 63;
    const int wid  = threadIdx.x >> 6;
    const int node = blockIdx.x * 4 + wid;
    if (node >= N_NODES) return;
    const int lo = off[node], hi = off[node + 1];

    float ldv[HEADS];
    #pragma unroll
    for (int hh = 0; hh < HEADS; ++hh) ldv[hh] = ld[node * HEADS + hh];

    // pass 1: max logit per head
    float m[HEADS];
    #pragma unroll
    for (int hh = 0; hh < HEADS; ++hh) m[hh] = -INFINITY;
    for (int e = lo + lane; e < hi; e += 64) {
        int s = ssrc[e];
        #pragma unroll
        for (int hh = 0; hh < HEADS; ++hh) {
            float l = leaky(ls[s * HEADS + hh] + ldv[hh]);
            m[hh] = fmaxf(m[hh], l);
        }
    }
    #pragma unroll
    for (int o = 1; o < 64; o <<= 1) {
        #pragma unroll
        for (int hh = 0; hh < HEADS; ++hh)
            m[hh] = fmaxf(m[hh], __shfl_xor(m[hh], o));
    }

    // pass 2: weighted accumulate; lane owns channel `lane` of each head
    float acc[HEADS] = {0.f, 0.f, 0.f, 0.f};
    float den[HEADS] = {0.f, 0.f, 0.f, 0.f};
    for (int e = lo; e < hi; ++e) {
        int s = ssrc[e];                       // wave-uniform
        const float* hr = h_in + (size_t)s * HID;
        float w[HEADS];
        #pragma unroll
        for (int hh = 0; hh < HEADS; ++hh) {
            float l = leaky(ls[s * HEADS + hh] + ldv[hh]);
            w[hh] = __expf(l - m[hh]);
            den[hh] += w[hh];
        }
        #pragma unroll
        for (int hh = 0; hh < HEADS; ++hh)
            acc[hh] += w[hh] * hr[hh * CHAN + lane];
    }
    #pragma unroll
    for (int hh = 0; hh < HEADS; ++hh) {
        float v = acc[hh] / (den[hh] + 1e-16f) + bias[hh * CHAN + lane];
        if (RELU) v = fmaxf(v, 0.f);
        h_out[(size_t)node * HID + hh * CHAN + lane] = v;
    }
}

// ---------------------------------------------------------------- pooling
__global__ __launch_bounds__(256) void pool_kernel(const float* __restrict__ h,
                                                   const int* __restrict__ batch,
                                                   float* __restrict__ pooled) {
    const int g = blockIdx.x;
    __shared__ int bounds[2];
    if (threadIdx.x < 2) {
        int target = g + threadIdx.x;          // lower_bound(batch, target)
        int lo = 0, hi = N_NODES;
        while (lo < hi) {
            int mid = (lo + hi) >> 1;
            if (batch[mid] < target) lo = mid + 1; else hi = mid;
        }
        bounds[threadIdx.x] = lo;
    }
    __syncthreads();
    const int lo = bounds[0], hi = bounds[1];
    const int c = threadIdx.x;                 // 256 threads = 256 channels
    float s = 0.f;
    for (int i = lo; i < hi; ++i) s += h[(size_t)i * HID + c];
    float cnt = (float)max(hi - lo, 1);
    pooled[(size_t)g * HID + c] = s / cnt;
}

// -------------------------------------------------------------- layernorm
__global__ __launch_bounds__(256) void ln_kernel(const float* __restrict__ z,
                                                 const float* __restrict__ gamma,
                                                 const float* __restrict__ beta,
                                                 float* __restrict__ out) {
    const int row = blockIdx.x;
    const float* zr = z + (size_t)row * NOUT;
    float v[3];
    float s = 0.f, s2 = 0.f;
    #pragma unroll
    for (int i = 0; i < 3; ++i) {
        v[i] = zr[threadIdx.x + i * 256];
        s += v[i];
        s2 += v[i] * v[i];
    }
    #pragma unroll
    for (int o = 32; o > 0; o >>= 1) {
        s  += __shfl_down(s, o);
        s2 += __shfl_down(s2, o);
    }
    __shared__ float red[8];
    const int wid = threadIdx.x >> 6, lane = threadIdx.x & 63;
    if (lane == 0) { red[wid] = s; red[4 + wid] = s2; }
    __syncthreads();
    if (threadIdx.x == 0) {
        float S  = red[0] + red[1] + red[2] + red[3];
        float S2 = red[4] + red[5] + red[6] + red[7];
        float mu  = S / NOUT;
        float var = S2 / NOUT - mu * mu;
        red[0] = mu;
        red[1] = rsqrtf(var + 1e-5f);
    }
    __syncthreads();
    float mu = red[0], rstd = red[1];
    #pragma unroll
    for (int i = 0; i < 3; ++i) {
        int c = threadIdx.x + i * 256;
        out[(size_t)row * NOUT + c] = gamma[c] * (v[i] - mu) * rstd + beta[c];
    }
}

// ------------------------------------------------------------------ launch
extern "C" void kernel_launch(void* const* d_in, const int* in_sizes, int n_in,
                              void* d_out, int out_size, void* d_ws, size_t ws_size,
                              hipStream_t stream) {
    const float* x     = (const float*)d_in[0];
    const int*   ei    = (const int*)d_in[1];
    const int*   batch = (const int*)d_in[2];
    const float* W1    = (const float*)d_in[3];
    const float* a_s1  = (const float*)d_in[4];
    const float* a_d1  = (const float*)d_in[5];
    const float* b1    = (const float*)d_in[6];
    const float* W2    = (const float*)d_in[7];
    const float* a_s2  = (const float*)d_in[8];
    const float* a_d2  = (const float*)d_in[9];
    const float* b2    = (const float*)d_in[10];
    const float* W3    = (const float*)d_in[11];
    const float* a_s3  = (const float*)d_in[12];
    const float* a_d3  = (const float*)d_in[13];
    const float* b3    = (const float*)d_in[14];
    const float* Wm1   = (const float*)d_in[15];
    const float* bm1   = (const float*)d_in[16];
    const float* Wm2   = (const float*)d_in[17];
    const float* bm2   = (const float*)d_in[18];
    const float* gamma = (const float*)d_in[19];
    const float* beta  = (const float*)d_in[20];
    float* out = (float*)d_out;

    char* p = (char*)d_ws;
    auto alloc = [&](size_t bytes) {
        void* r = (void*)p;
        p += (bytes + 255) & ~(size_t)255;
        return r;
    };
    int*   deg    = (int*)  alloc((size_t)N_NODES * 4);
    int*   off    = (int*)  alloc((size_t)(N_NODES + 1) * 4);
    int*   cur    = (int*)  alloc((size_t)N_NODES * 4);
    int*   ssrc   = (int*)  alloc((size_t)N_ETOT * 4);
    float* ls     = (float*)alloc((size_t)N_NODES * HEADS * 4);
    float* ld     = (float*)alloc((size_t)N_NODES * HEADS * 4);
    float* hA     = (float*)alloc((size_t)N_NODES * HID * 4);
    float* hB     = (float*)alloc((size_t)N_NODES * HID * 4);
    float* pooled = (float*)alloc((size_t)NGRAPH * HID * 4);
    float* z1     = (float*)alloc((size_t)NGRAPH * MLP_HID * 4);
    float* z2     = (float*)alloc((size_t)NGRAPH * NOUT * 4);

    // ---- CSR by dst (shared by all layers)
    hipMemsetAsync(deg, 0, (size_t)N_NODES * 4, stream);
    hist_kernel<<<(N_ETOT + 255) / 256, 256, 0, stream>>>(ei, deg);
    scan_kernel<<<1, 1024, 0, stream>>>(deg, off, cur);
    scatter_kernel<<<(N_ETOT + 255) / 256, 256, 0, stream>>>(ei, cur, ssrc);

    const int nodeBlocks = (N_NODES + 3) / 4;       // 4 waves/block, wave/node
    dim3 gemmN((N_NODES + 63) / 64, HID / 64);

    // ---- layer 1
    gemm_kernel<false, false><<<gemmN, 256, 0, stream>>>(x, W1, nullptr, hA, N_NODES, HID, F_IN);
    logits_kernel<<<nodeBlocks, 256, 0, stream>>>(hA, a_s1, a_d1, ls, ld);
    gat_aggregate<true><<<nodeBlocks, 256, 0, stream>>>(hA, off, ssrc, ls, ld, b1, hB);

    // ---- layer 2
    gemm_kernel<false, false><<<gemmN, 256, 0, stream>>>(hB, W2, nullptr, hA, N_NODES, HID, HID);
    logits_kernel<<<nodeBlocks, 256, 0, stream>>>(hA, a_s2, a_d2, ls, ld);
    gat_aggregate<true><<<nodeBlocks, 256, 0, stream>>>(hA, off, ssrc, ls, ld, b2, hB);

    // ---- layer 3 (no relu)
    gemm_kernel<false, false><<<gemmN, 256, 0, stream>>>(hB, W3, nullptr, hA, N_NODES, HID, HID);
    logits_kernel<<<nodeBlocks, 256, 0, stream>>>(hA, a_s3, a_d3, ls, ld);
    gat_aggregate<false><<<nodeBlocks, 256, 0, stream>>>(hA, off, ssrc, ls, ld, b3, hB);

    // ---- pool + MLP + layernorm
    pool_kernel<<<NGRAPH, 256, 0, stream>>>(hB, batch, pooled);
    dim3 gm1(NGRAPH / 64, MLP_HID / 64);
    gemm_kernel<true, true><<<gm1, 256, 0, stream>>>(pooled, Wm1, bm1, z1, NGRAPH, MLP_HID, HID);
    dim3 gm2(NGRAPH / 64, NOUT / 64);
    gemm_kernel<true, false><<<gm2, 256, 0, stream>>>(z1, Wm2, bm2, z2, NGRAPH, NOUT, MLP_HID);
    ln_kernel<<<NGRAPH, 256, 0, stream>>>(z2, gamma, beta, out);
}

// Round 5
// 1177.020 us; speedup vs baseline: 1.3632x; 1.3632x over previous
//
#include <hip/hip_runtime.h>
#include <math.h>

#define N_NODES 50000
#define N_EDGES 800000
#define N_ETOT  850000   /* E + N self-loops */
#define F_IN    32
#define HEADS   4
#define CHAN    64
#define HID     256
#define NGRAPH  1024
#define MLP_HID 2048
#define NOUT    768
#define NEG_SLOPE 0.2f

// ---------------------------------------------------------------- CSR build
__global__ __launch_bounds__(256) void hist_kernel(const int* __restrict__ ei,
                                                   int* __restrict__ deg) {
    int e = blockIdx.x * 256 + threadIdx.x;
    if (e >= N_ETOT) return;
    int d = (e < N_EDGES) ? ei[N_EDGES + e] : (e - N_EDGES);
    atomicAdd(&deg[d], 1);
}

__global__ __launch_bounds__(1024) void scan_kernel(const int* __restrict__ deg,
                                                    int* __restrict__ off,
                                                    int* __restrict__ cur) {
    __shared__ int sums[1024];
    const int t = threadIdx.x;
    const int CHK = (N_NODES + 1023) / 1024;   // 49
    int lo = t * CHK;
    int hi = min(lo + CHK, N_NODES);
    int s = 0;
    for (int i = lo; i < hi; ++i) s += deg[i];
    sums[t] = s;
    __syncthreads();
    for (int d = 1; d < 1024; d <<= 1) {
        int v = (t >= d) ? sums[t - d] : 0;
        __syncthreads();
        sums[t] += v;
        __syncthreads();
    }
    int run = sums[t] - s;                     // exclusive prefix
    for (int i = lo; i < hi; ++i) {
        int d0 = deg[i];
        off[i] = run;
        cur[i] = run;
        run += d0;
    }
    if (t == 1023) off[N_NODES] = run;
}

__global__ __launch_bounds__(256) void scatter_kernel(const int* __restrict__ ei,
                                                      int* __restrict__ cur,
                                                      int* __restrict__ ssrc) {
    int e = blockIdx.x * 256 + threadIdx.x;
    if (e >= N_ETOT) return;
    int s, d;
    if (e < N_EDGES) { s = ei[e]; d = ei[N_EDGES + e]; }
    else             { s = e - N_EDGES; d = s; }
    int pos = atomicAdd(&cur[d], 1);
    ssrc[pos] = s;
}

// ---------------------------------------------------------------- fp32 GEMM
// C[M,Nn] = A[M,K] @ B[K,Nn] (+bias)(+relu).
// As stored TRANSPOSED As[k][m] (pad +4 keeps 16B alignment) so both
// fragments read as ds_read_b128. BK=16, 256 threads, TMxTN micro-tile.
template <int BM, int BN, int TM, int TN, bool BIAS, bool RELU>
__global__ __launch_bounds__(256) void gemm_kernel(const float* __restrict__ A,
                                                   const float* __restrict__ B,
                                                   const float* __restrict__ bias,
                                                   float* __restrict__ C,
                                                   int M, int Nn, int K) {
    __shared__ float As[16][BM + 4];
    __shared__ float Bs[16][BN + 4];
    const int t = threadIdx.x;
    const int bm = blockIdx.x * BM;
    const int bn = blockIdx.y * BN;
    constexpr int NTX = BN / TN;               // threads along N
    const int tx = t % NTX;
    const int ty = t / NTX;
    const int row0 = ty * TM;
    const int col0 = tx * TN;
    constexpr int AITER = BM * 4 / 256;        // float4s per thread for A tile
    constexpr int BN4 = BN / 4;
    constexpr int BITER = 16 * BN4 / 256;

    float acc[TM][TN] = {};
    for (int k0 = 0; k0 < K; k0 += 16) {
        #pragma unroll
        for (int it = 0; it < AITER; ++it) {
            int f = t + it * 256;
            int m = f >> 2, k4 = (f & 3) << 2;
            int gr = bm + m;
            float4 v = make_float4(0.f, 0.f, 0.f, 0.f);
            if (gr < M) v = *(const float4*)&A[(size_t)gr * K + k0 + k4];
            As[k4 + 0][m] = v.x;
            As[k4 + 1][m] = v.y;
            As[k4 + 2][m] = v.z;
            As[k4 + 3][m] = v.w;
        }
        #pragma unroll
        for (int it = 0; it < BITER; ++it) {
            int f = t + it * 256;
            int k = f / BN4, n = (f % BN4) << 2;
            *(float4*)&Bs[k][n] = *(const float4*)&B[(size_t)(k0 + k) * Nn + bn + n];
        }
        __syncthreads();
        #pragma unroll
        for (int k = 0; k < 16; ++k) {
            float a[TM], b[TN];
            #pragma unroll
            for (int i = 0; i < TM; i += 4)
                *(float4*)&a[i] = *(const float4*)&As[k][row0 + i];
            #pragma unroll
            for (int j = 0; j < TN; j += 4)
                *(float4*)&b[j] = *(const float4*)&Bs[k][col0 + j];
            #pragma unroll
            for (int i = 0; i < TM; ++i)
                #pragma unroll
                for (int j = 0; j < TN; ++j)
                    acc[i][j] += a[i] * b[j];
        }
        __syncthreads();
    }
    #pragma unroll
    for (int i = 0; i < TM; ++i) {
        int r = bm + row0 + i;
        if (r >= M) continue;
        #pragma unroll
        for (int j = 0; j < TN; j += 4) {
            int c = bn + col0 + j;
            float4 v;
            v.x = acc[i][j + 0];
            v.y = acc[i][j + 1];
            v.z = acc[i][j + 2];
            v.w = acc[i][j + 3];
            if (BIAS) {
                const float4 bv = *(const float4*)&bias[c];
                v.x += bv.x; v.y += bv.y; v.z += bv.z; v.w += bv.w;
            }
            if (RELU) {
                v.x = fmaxf(v.x, 0.f); v.y = fmaxf(v.y, 0.f);
                v.z = fmaxf(v.z, 0.f); v.w = fmaxf(v.w, 0.f);
            }
            *(float4*)&C[(size_t)r * Nn + c] = v;
        }
    }
}

// ------------------------------------------------------- attention logits
__global__ __launch_bounds__(256) void logits_kernel(const float* __restrict__ h,
                                                     const float* __restrict__ a_s,
                                                     const float* __restrict__ a_d,
                                                     float* __restrict__ ls,
                                                     float* __restrict__ ld) {
    const int lane = threadIdx.x & 63;
    const int wid  = threadIdx.x >> 6;
    const int node = blockIdx.x * 4 + wid;
    if (node >= N_NODES) return;
    float ss[HEADS], dd[HEADS];
    #pragma unroll
    for (int hh = 0; hh < HEADS; ++hh) {
        float v = h[(size_t)node * HID + hh * CHAN + lane];
        ss[hh] = v * a_s[hh * CHAN + lane];
        dd[hh] = v * a_d[hh * CHAN + lane];
    }
    #pragma unroll
    for (int o = 32; o > 0; o >>= 1) {
        #pragma unroll
        for (int hh = 0; hh < HEADS; ++hh) {
            ss[hh] += __shfl_down(ss[hh], o);
            dd[hh] += __shfl_down(dd[hh], o);
        }
    }
    if (lane == 0) {
        #pragma unroll
        for (int hh = 0; hh < HEADS; ++hh) {
            ls[node * HEADS + hh] = ss[hh];
            ld[node * HEADS + hh] = dd[hh];
        }
    }
}

// --------------------------------------------------------- GAT aggregation
// wave per dst node; lane owns 4 CONSECUTIVE channels (float4 gather) and
// only its own head's weight. Pass 1: 16-lane-group segment max.
__device__ __forceinline__ float leaky(float x) { return fmaxf(x, NEG_SLOPE * x); }

template <bool RELU>
__global__ __launch_bounds__(256) void gat_aggregate(const float* __restrict__ h_in,
                                                     const int* __restrict__ off,
                                                     const int* __restrict__ ssrc,
                                                     const float* __restrict__ ls,
                                                     const float* __restrict__ ld,
                                                     const float* __restrict__ bias,
                                                     float* __restrict__ h_out) {
    const int lane = threadIdx.x & 63;
    const int wid  = threadIdx.x >> 6;
    const int node = blockIdx.x * 4 + wid;
    if (node >= N_NODES) return;
    const int lo = off[node], hi = off[node + 1];
    const int myh = lane >> 4;                 // head of channels 4*lane..4*lane+3
    const float ldv = ld[node * HEADS + myh];

    // pass 1: per-head max over segment (16 lanes of the head group stride edges)
    float m = -INFINITY;
    for (int e = lo + (lane & 15); e < hi; e += 16) {
        int s = ssrc[e];
        m = fmaxf(m, leaky(ls[s * HEADS + myh] + ldv));
    }
    #pragma unroll
    for (int o = 1; o < 16; o <<= 1) m = fmaxf(m, __shfl_xor(m, o));

    // pass 2: weighted accumulate, float4 per lane
    float4 acc = make_float4(0.f, 0.f, 0.f, 0.f);
    float den = 0.f;
    for (int e = lo; e < hi; ++e) {
        int s = ssrc[e];                       // wave-uniform
        float w = __expf(leaky(ls[s * HEADS + myh] + ldv) - m);
        den += w;
        float4 hv = *(const float4*)(h_in + (size_t)s * HID + lane * 4);
        acc.x += w * hv.x; acc.y += w * hv.y;
        acc.z += w * hv.z; acc.w += w * hv.w;
    }
    float inv = 1.f / (den + 1e-16f);
    float4 bv = *(const float4*)(bias + lane * 4);
    float4 o;
    o.x = acc.x * inv + bv.x; o.y = acc.y * inv + bv.y;
    o.z = acc.z * inv + bv.z; o.w = acc.w * inv + bv.w;
    if (RELU) {
        o.x = fmaxf(o.x, 0.f); o.y = fmaxf(o.y, 0.f);
        o.z = fmaxf(o.z, 0.f); o.w = fmaxf(o.w, 0.f);
    }
    *(float4*)(h_out + (size_t)node * HID + lane * 4) = o;
}

// ---------------------------------------------------------------- pooling
__global__ __launch_bounds__(256) void pool_kernel(const float* __restrict__ h,
                                                   const int* __restrict__ batch,
                                                   float* __restrict__ pooled) {
    const int g = blockIdx.x;
    __shared__ int bounds[2];
    if (threadIdx.x < 2) {
        int target = g + threadIdx.x;
        int lo = 0, hi = N_NODES;
        while (lo < hi) {
            int mid = (lo + hi) >> 1;
            if (batch[mid] < target) lo = mid + 1; else hi = mid;
        }
        bounds[threadIdx.x] = lo;
    }
    __syncthreads();
    const int lo = bounds[0], hi = bounds[1];
    const int c = threadIdx.x;
    float s = 0.f;
    for (int i = lo; i < hi; ++i) s += h[(size_t)i * HID + c];
    float cnt = (float)max(hi - lo, 1);
    pooled[(size_t)g * HID + c] = s / cnt;
}

// -------------------------------------------------------------- layernorm
__global__ __launch_bounds__(256) void ln_kernel(const float* __restrict__ z,
                                                 const float* __restrict__ gamma,
                                                 const float* __restrict__ beta,
                                                 float* __restrict__ out) {
    const int row = blockIdx.x;
    const float* zr = z + (size_t)row * NOUT;
    float v[3];
    float s = 0.f, s2 = 0.f;
    #pragma unroll
    for (int i = 0; i < 3; ++i) {
        v[i] = zr[threadIdx.x + i * 256];
        s += v[i];
        s2 += v[i] * v[i];
    }
    #pragma unroll
    for (int o = 32; o > 0; o >>= 1) {
        s  += __shfl_down(s, o);
        s2 += __shfl_down(s2, o);
    }
    __shared__ float red[8];
    const int wid = threadIdx.x >> 6, lane = threadIdx.x & 63;
    if (lane == 0) { red[wid] = s; red[4 + wid] = s2; }
    __syncthreads();
    if (threadIdx.x == 0) {
        float S  = red[0] + red[1] + red[2] + red[3];
        float S2 = red[4] + red[5] + red[6] + red[7];
        float mu  = S / NOUT;
        float var = S2 / NOUT - mu * mu;
        red[0] = mu;
        red[1] = rsqrtf(var + 1e-5f);
    }
    __syncthreads();
    float mu = red[0], rstd = red[1];
    #pragma unroll
    for (int i = 0; i < 3; ++i) {
        int c = threadIdx.x + i * 256;
        out[(size_t)row * NOUT + c] = gamma[c] * (v[i] - mu) * rstd + beta[c];
    }
}

// ------------------------------------------------------------------ launch
extern "C" void kernel_launch(void* const* d_in, const int* in_sizes, int n_in,
                              void* d_out, int out_size, void* d_ws, size_t ws_size,
                              hipStream_t stream) {
    const float* x     = (const float*)d_in[0];
    const int*   ei    = (const int*)d_in[1];
    const int*   batch = (const int*)d_in[2];
    const float* W1    = (const float*)d_in[3];
    const float* a_s1  = (const float*)d_in[4];
    const float* a_d1  = (const float*)d_in[5];
    const float* b1    = (const float*)d_in[6];
    const float* W2    = (const float*)d_in[7];
    const float* a_s2  = (const float*)d_in[8];
    const float* a_d2  = (const float*)d_in[9];
    const float* b2    = (const float*)d_in[10];
    const float* W3    = (const float*)d_in[11];
    const float* a_s3  = (const float*)d_in[12];
    const float* a_d3  = (const float*)d_in[13];
    const float* b3    = (const float*)d_in[14];
    const float* Wm1   = (const float*)d_in[15];
    const float* bm1   = (const float*)d_in[16];
    const float* Wm2   = (const float*)d_in[17];
    const float* bm2   = (const float*)d_in[18];
    const float* gamma = (const float*)d_in[19];
    const float* beta  = (const float*)d_in[20];
    float* out = (float*)d_out;

    char* p = (char*)d_ws;
    auto alloc = [&](size_t bytes) {
        void* r = (void*)p;
        p += (bytes + 255) & ~(size_t)255;
        return r;
    };
    int*   deg    = (int*)  alloc((size_t)N_NODES * 4);
    int*   off    = (int*)  alloc((size_t)(N_NODES + 1) * 4);
    int*   cur    = (int*)  alloc((size_t)N_NODES * 4);
    int*   ssrc   = (int*)  alloc((size_t)N_ETOT * 4);
    float* ls     = (float*)alloc((size_t)N_NODES * HEADS * 4);
    float* ld     = (float*)alloc((size_t)N_NODES * HEADS * 4);
    float* hA     = (float*)alloc((size_t)N_NODES * HID * 4);
    float* hB     = (float*)alloc((size_t)N_NODES * HID * 4);
    float* pooled = (float*)alloc((size_t)NGRAPH * HID * 4);
    float* z1     = (float*)alloc((size_t)NGRAPH * MLP_HID * 4);
    float* z2     = (float*)alloc((size_t)NGRAPH * NOUT * 4);

    // ---- CSR by dst (shared by all layers)
    hipMemsetAsync(deg, 0, (size_t)N_NODES * 4, stream);
    hist_kernel<<<(N_ETOT + 255) / 256, 256, 0, stream>>>(ei, deg);
    scan_kernel<<<1, 1024, 0, stream>>>(deg, off, cur);
    scatter_kernel<<<(N_ETOT + 255) / 256, 256, 0, stream>>>(ei, cur, ssrc);

    const int nodeBlocks = (N_NODES + 3) / 4;
    dim3 gemmN((N_NODES + 127) / 128, HID / 128);   // 391 x 2

    // ---- layer 1
    gemm_kernel<128, 128, 8, 8, false, false><<<gemmN, 256, 0, stream>>>(x, W1, nullptr, hA, N_NODES, HID, F_IN);
    logits_kernel<<<nodeBlocks, 256, 0, stream>>>(hA, a_s1, a_d1, ls, ld);
    gat_aggregate<true><<<nodeBlocks, 256, 0, stream>>>(hA, off, ssrc, ls, ld, b1, hB);

    // ---- layer 2
    gemm_kernel<128, 128, 8, 8, false, false><<<gemmN, 256, 0, stream>>>(hB, W2, nullptr, hA, N_NODES, HID, HID);
    logits_kernel<<<nodeBlocks, 256, 0, stream>>>(hA, a_s2, a_d2, ls, ld);
    gat_aggregate<true><<<nodeBlocks, 256, 0, stream>>>(hA, off, ssrc, ls, ld, b2, hB);

    // ---- layer 3 (no relu)
    gemm_kernel<128, 128, 8, 8, false, false><<<gemmN, 256, 0, stream>>>(hB, W3, nullptr, hA, N_NODES, HID, HID);
    logits_kernel<<<nodeBlocks, 256, 0, stream>>>(hA, a_s3, a_d3, ls, ld);
    gat_aggregate<false><<<nodeBlocks, 256, 0, stream>>>(hA, off, ssrc, ls, ld, b3, hB);

    // ---- pool + MLP + layernorm
    pool_kernel<<<NGRAPH, 256, 0, stream>>>(hB, batch, pooled);
    dim3 gm1(NGRAPH / 64, MLP_HID / 128);           // 16 x 16 = 256 blocks
    gemm_kernel<64, 128, 4, 8, true, true><<<gm1, 256, 0, stream>>>(pooled, Wm1, bm1, z1, NGRAPH, MLP_HID, HID);
    dim3 gm2(NGRAPH / 64, NOUT / 64);               // 16 x 12 = 192 blocks
    gemm_kernel<64, 64, 4, 4, true, false><<<gm2, 256, 0, stream>>>(z1, Wm2, bm2, z2, NGRAPH, NOUT, MLP_HID);
    ln_kernel<<<NGRAPH, 256, 0, stream>>>(z2, gamma, beta, out);
}